// Round 8
// baseline (361.918 us; speedup 1.0000x reference)
//
#include <hip/hip_runtime.h>

// GIN regressor: 3x [segment-sum aggregation -> (1+eps)*x+agg -> Linear/ReLU/Linear]
// -> global mean pool -> fc.
// CSR built once per call via LDS-binned coarse-bucket counting sort: each block
// bins a 10K-edge chunk entirely in LDS, reserves per-bucket global ranges with
// ONE atomic per (block,bucket), and writes contiguous runs (kills the 12-16x
// scattered-store write amplification seen in rounds 6/7). Aggregation is
// gather-only over bf16 tables. GEMMs = bf16 MFMA (fp32 accum, pre-swizzled W).
// Layer-2: second GEMM folded into pool (weff = W2@fcw); its first GEMM's
// epilogue computes pooled per-graph sums directly.

#define FEAT 128
#define BCAP 2048          // per-bucket capacity (mean load ~1024)
#define CHUNK 10240        // edges per bucket-kernel block

typedef short  bf16x8 __attribute__((ext_vector_type(8)));
typedef float  f32x4  __attribute__((ext_vector_type(4)));

__device__ inline unsigned short f2bf(float f) {  // round-to-nearest-even fp32->bf16
    unsigned int u = __float_as_uint(f);
    u = (u + 0x7FFFu + ((u >> 16) & 1u)) >> 16;
    return (unsigned short)u;
}
__device__ inline float2 bfpair(unsigned int u) { // packed 2x bf16 -> 2x fp32
    float2 r;
    r.x = __uint_as_float(u << 16);
    r.y = __uint_as_float(u & 0xffff0000u);
    return r;
}

// ---------------- CSR build: LDS-binned coarse-bucket counting sort ----------
// Phase 1: per-chunk LDS bin by dst>>6, then coalesced run writes.
__global__ __launch_bounds__(256) void bucket_kernel(
    const int* __restrict__ src, const int* __restrict__ dst,
    int* __restrict__ bcnt, unsigned int* __restrict__ bpairs, int E) {
    __shared__ unsigned int lpairs[CHUNK];   // 40KB: bucket-ordered pairs
    __shared__ int lbase[1025];              // chunk-local exclusive offsets
    __shared__ int lcur[1024];               // counters, then cursors
    __shared__ int lres[1024];               // global reservation base per bucket
    __shared__ int part[256];
    int tid = threadIdx.x;
    int e0 = blockIdx.x * CHUNK;
    int e1 = e0 + CHUNK; if (e1 > E) e1 = E;
    int cnt = e1 - e0;
    #pragma unroll
    for (int i = 0; i < 4; ++i) lcur[tid + 256 * i] = 0;
    __syncthreads();
    for (int e = e0 + tid; e < e1; e += 256) atomicAdd(&lcur[dst[e] >> 6], 1);
    __syncthreads();
    // exclusive scan of 1024 counters (4 per thread + Hillis-Steele partials)
    int v0 = lcur[4 * tid], v1 = lcur[4 * tid + 1], v2 = lcur[4 * tid + 2], v3 = lcur[4 * tid + 3];
    part[tid] = v0 + v1 + v2 + v3;
    __syncthreads();
    for (int d = 1; d < 256; d <<= 1) {
        int u = (tid >= d) ? part[tid - d] : 0;
        __syncthreads();
        part[tid] += u;
        __syncthreads();
    }
    int ex = (tid == 0) ? 0 : part[tid - 1];
    lbase[4 * tid] = ex;
    lbase[4 * tid + 1] = ex + v0;
    lbase[4 * tid + 2] = ex + v0 + v1;
    lbase[4 * tid + 3] = ex + v0 + v1 + v2;
    if (tid == 255) lbase[1024] = part[255];
    __syncthreads();
    // cursors + one global reservation per (block,bucket)
    #pragma unroll
    for (int i = 0; i < 4; ++i) {
        int b = tid + 256 * i;
        lcur[b] = lbase[b];
        int c = lbase[b + 1] - lbase[b];
        lres[b] = (c > 0) ? atomicAdd(&bcnt[b * 16], c) : 0;
    }
    __syncthreads();
    // place pairs bucket-ordered in LDS
    for (int e = e0 + tid; e < e1; e += 256) {
        int d = dst[e], s = src[e];
        int p = atomicAdd(&lcur[d >> 6], 1);
        lpairs[p] = ((unsigned int)s << 6) | (unsigned int)(d & 63);
    }
    __syncthreads();
    // coalesced writeout: consecutive j -> consecutive slots of the same run
    for (int j = tid; j < cnt; j += 256) {
        int lo = 0, hi = 1023;
        while (lo < hi) { int m = (lo + hi + 1) >> 1; if (lbase[m] <= j) lo = m; else hi = m - 1; }
        int gpos = lres[lo] + (j - lbase[lo]);
        if (gpos < BCAP) bpairs[(size_t)lo * BCAP + gpos] = lpairs[j];
    }
}

// Phase 2: per-bucket LDS histogram -> node degrees.
__global__ __launch_bounds__(256) void deg_kernel(const int* __restrict__ bcnt,
                                                  const unsigned int* __restrict__ bpairs,
                                                  int* __restrict__ off, int n) {
    __shared__ int lh[64];
    int b = blockIdx.x, tid = threadIdx.x;
    if (tid < 64) lh[tid] = 0;
    __syncthreads();
    int cnt = bcnt[b * 16]; if (cnt > BCAP) cnt = BCAP;
    const unsigned int* bp = bpairs + (size_t)b * BCAP;
    for (int i = tid; i < cnt; i += 256) atomicAdd(&lh[bp[i] & 63u], 1);
    __syncthreads();
    if (tid < 64) {
        int node = b * 64 + tid;
        if (node < n) off[node] = lh[tid];
    }
}

// Phase A: blocksums[b] = sum(off[b*1024 .. +1023])
__global__ void block_sum_kernel(const int* __restrict__ off, int* __restrict__ bs, int n) {
    int b = blockIdx.x, t = threadIdx.x;   // 256 threads
    int base = b * 1024;
    int s = 0;
    #pragma unroll
    for (int i = 0; i < 4; ++i) {
        int idx = base + t + 256 * i;
        if (idx < n) s += off[idx];
    }
    #pragma unroll
    for (int d = 32; d; d >>= 1) s += __shfl_down(s, d, 64);
    __shared__ int ws[4];
    if ((t & 63) == 0) ws[t >> 6] = s;
    __syncthreads();
    if (t == 0) bs[b] = ws[0] + ws[1] + ws[2] + ws[3];
}

__global__ void scan_blocksums_kernel(int* __restrict__ bs, int nb,
                                      int* __restrict__ off, int n) {
    __shared__ int l[1024];
    int t = threadIdx.x;
    int v = (t < nb) ? bs[t] : 0;
    l[t] = v;
    __syncthreads();
    for (int d = 1; d < 1024; d <<= 1) {
        int u = (t >= d) ? l[t - d] : 0;
        __syncthreads();
        l[t] += u;
        __syncthreads();
    }
    if (t < nb) bs[t] = (t == 0) ? 0 : l[t - 1];
    if (t == 1023) off[n] = l[1023];
}

__global__ __launch_bounds__(256) void block_scan_kernel(
    int* __restrict__ off, const int* __restrict__ bs, int n) {
    __shared__ int l[1024];
    __shared__ int part[256];
    int b = blockIdx.x, t = threadIdx.x;
    int base = b * 1024;
    #pragma unroll
    for (int i = 0; i < 4; ++i) {
        int idx = base + t + 256 * i;
        l[t + 256 * i] = (idx < n) ? off[idx] : 0;
    }
    __syncthreads();
    int v0 = l[4 * t], v1 = l[4 * t + 1], v2 = l[4 * t + 2], v3 = l[4 * t + 3];
    int p = v0 + v1 + v2 + v3;
    part[t] = p;
    __syncthreads();
    for (int d = 1; d < 256; d <<= 1) {
        int u = (t >= d) ? part[t - d] : 0;
        __syncthreads();
        part[t] += u;
        __syncthreads();
    }
    int ex = bs[b] + ((t == 0) ? 0 : part[t - 1]);
    int e0 = ex, e1 = ex + v0, e2 = e1 + v1, e3 = e2 + v2;
    int idx = base + 4 * t;
    if (idx + 3 < n) {
        ((int4*)(off + idx))[0] = make_int4(e0, e1, e2, e3);
    } else {
        if (idx + 0 < n) off[idx + 0] = e0;
        if (idx + 1 < n) off[idx + 1] = e1;
        if (idx + 2 < n) off[idx + 2] = e2;
    }
}

// Phase 3: per-bucket scatter with LDS cursors; writes confined to ~4KB region.
__global__ __launch_bounds__(256) void bucket_scatter_kernel(
    const int* __restrict__ bcnt, const unsigned int* __restrict__ bpairs,
    const int* __restrict__ off, int* __restrict__ srcs, int n) {
    __shared__ int lcur[64];
    int b = blockIdx.x, tid = threadIdx.x;
    if (tid < 64) {
        int node = b * 64 + tid;
        lcur[tid] = (node < n) ? off[node] : 0;
    }
    __syncthreads();
    int cnt = bcnt[b * 16]; if (cnt > BCAP) cnt = BCAP;
    const unsigned int* bp = bpairs + (size_t)b * BCAP;
    for (int i = tid; i < cnt; i += 256) {
        unsigned int pr = bp[i];
        int pos = atomicAdd(&lcur[pr & 63u], 1);
        srcs[pos] = (int)(pr >> 6);
    }
}

// ---------------- fused setup: xbf | gstart | weff | wprep ----------------
__global__ __launch_bounds__(256) void setup_kernel(
    const float* __restrict__ x, unsigned int* __restrict__ xbf, long pairs, int nxb,
    const int* __restrict__ batch, int* __restrict__ gstart, int n, int G,
    const float* __restrict__ W2f, const float* __restrict__ b2f,
    const float* __restrict__ fcw, float* __restrict__ weff,
    const float* __restrict__ W0, const float* __restrict__ W1,
    const float* __restrict__ W2, const float* __restrict__ W3,
    const float* __restrict__ W4, unsigned short* __restrict__ Wswz) {
    int b = blockIdx.x, tid = threadIdx.x;
    if (b < nxb) {                       // cast x -> packed bf16
        long i = (long)b * 256 + tid;
        if (i < pairs) {
            float2 v = ((const float2*)x)[i];
            xbf[i] = (unsigned int)f2bf(v.x) | ((unsigned int)f2bf(v.y) << 16);
        }
    } else if (b < nxb + 2) {            // gstart[g] = lower_bound(batch, g)
        int i = (b - nxb) * 256 + tid;
        if (i <= G) {
            int lo = 0, hi = n;
            while (lo < hi) { int m = (lo + hi) >> 1; if (batch[m] < i) lo = m + 1; else hi = m; }
            gstart[i] = lo;
        }
    } else if (b == nxb + 2) {           // weff = W2@fcw ; weff[128] = b2.fcw
        int lane = tid & 63, wave = tid >> 6;
        float2 f2 = ((const float2*)fcw)[lane];
        for (int r = wave; r < 128; r += 4) {
            float2 w = ((const float2*)(W2f + r * FEAT))[lane];
            float d = w.x * f2.x + w.y * f2.y;
            #pragma unroll
            for (int s = 32; s; s >>= 1) d += __shfl_down(d, s, 64);
            if (lane == 0) weff[r] = d;
        }
        if (wave == 0) {
            float2 bb = ((const float2*)b2f)[lane];
            float d = bb.x * f2.x + bb.y * f2.y;
            #pragma unroll
            for (int s = 32; s; s >>= 1) d += __shfl_down(d, s, 64);
            if (lane == 0) weff[128] = d;
        }
    } else {                             // wprep: swizzled bf16 weights
        int gid = (b - nxb - 3) * 256 + tid;
        if (gid < 5 * 2048) {
            int mat = gid >> 11;
            int task = gid & 2047;
            int c = task >> 4, m = task & 15;
            const float* W = (mat == 0) ? W0 : (mat == 1) ? W1 : (mat == 2) ? W2 :
                             (mat == 3) ? W3 : W4;
            unsigned short* dp = Wswz + mat * 16384 + c * 128 + ((m ^ (c & 7)) << 3);
            #pragma unroll
            for (int j = 0; j < 8; ++j) dp[j] = f2bf(W[(8 * m + j) * FEAT + c]);
        }
    }
}

// ---------------- aggregation + (1+eps)*h -> bf16 pre ----------------
__global__ void agg_kernel(const unsigned int* __restrict__ h, const int* __restrict__ off,
                           const int* __restrict__ srcs, const float* __restrict__ eps_p,
                           unsigned int* __restrict__ pre_bf, int n) {
    int wave = (int)((blockIdx.x * (size_t)blockDim.x + threadIdx.x) >> 6);
    int lane = threadIdx.x & 63;
    if (wave >= n) return;
    float eps1 = 1.0f + eps_p[0];
    float2 self = bfpair(h[(size_t)wave * 64 + lane]);
    float2 acc0 = make_float2(self.x * eps1, self.y * eps1);
    float2 acc1 = make_float2(0.f, 0.f);
    float2 acc2 = make_float2(0.f, 0.f);
    float2 acc3 = make_float2(0.f, 0.f);
    int j0 = off[wave], j1 = off[wave + 1];
    int j = j0;
    for (; j + 8 <= j1; j += 8) {
        int s0 = srcs[j + 0], s1 = srcs[j + 1], s2 = srcs[j + 2], s3 = srcs[j + 3];
        int s4 = srcs[j + 4], s5 = srcs[j + 5], s6 = srcs[j + 6], s7 = srcs[j + 7];
        unsigned int u0 = h[(size_t)s0 * 64 + lane];
        unsigned int u1 = h[(size_t)s1 * 64 + lane];
        unsigned int u2 = h[(size_t)s2 * 64 + lane];
        unsigned int u3 = h[(size_t)s3 * 64 + lane];
        unsigned int u4 = h[(size_t)s4 * 64 + lane];
        unsigned int u5 = h[(size_t)s5 * 64 + lane];
        unsigned int u6 = h[(size_t)s6 * 64 + lane];
        unsigned int u7 = h[(size_t)s7 * 64 + lane];
        float2 v0 = bfpair(u0), v1 = bfpair(u1), v2 = bfpair(u2), v3 = bfpair(u3);
        float2 v4 = bfpair(u4), v5 = bfpair(u5), v6 = bfpair(u6), v7 = bfpair(u7);
        acc0.x += v0.x; acc0.y += v0.y;  acc1.x += v1.x; acc1.y += v1.y;
        acc2.x += v2.x; acc2.y += v2.y;  acc3.x += v3.x; acc3.y += v3.y;
        acc0.x += v4.x; acc0.y += v4.y;  acc1.x += v5.x; acc1.y += v5.y;
        acc2.x += v6.x; acc2.y += v6.y;  acc3.x += v7.x; acc3.y += v7.y;
    }
    for (; j < j1; ++j) {
        int s = srcs[j];
        float2 v = bfpair(h[(size_t)s * 64 + lane]);
        acc0.x += v.x; acc0.y += v.y;
    }
    acc0.x += acc1.x + acc2.x + acc3.x;
    acc0.y += acc1.y + acc2.y + acc3.y;
    pre_bf[(size_t)wave * 64 + lane] =
        (unsigned int)f2bf(acc0.x) | ((unsigned int)f2bf(acc0.y) << 16);
}

// ---------------- bf16 MFMA GEMM (+ReLU). MODE 1: bf16 store. MODE 2: fused pool ----
template <int MODE>
__global__ __launch_bounds__(256) void mfma_mlp_kernel(
    const unsigned short* __restrict__ A, const unsigned short* __restrict__ Wswz,
    const float* __restrict__ bias, unsigned short* __restrict__ outbf,
    const int* __restrict__ batch, const float* __restrict__ weff,
    float* __restrict__ sums, int n) {
    __shared__ int4 Wl4[2048];   // 32KB swizzled W
    int tid = threadIdx.x;
    const int4* ws4 = (const int4*)Wswz;
    #pragma unroll
    for (int i = 0; i < 8; ++i) Wl4[i * 256 + tid] = ws4[i * 256 + tid];
    __syncthreads();
    const unsigned short* Wl = (const unsigned short*)Wl4;

    int lane = tid & 63, wave = tid >> 6;
    int q = lane >> 4, c15 = lane & 15;
    int r0 = blockIdx.x * 64 + wave * 16;
    int arow = r0 + c15;
    bool rv = arow < n;
    const bf16x8* ap = (const bf16x8*)(A + (size_t)arow * FEAT + q * 8);

    f32x4 zf = {0.f, 0.f, 0.f, 0.f};
    f32x4 acc[8];
    #pragma unroll
    for (int i = 0; i < 8; ++i) acc[i] = zf;
    bf16x8 zero8 = {0, 0, 0, 0, 0, 0, 0, 0};

    #pragma unroll
    for (int k0 = 0; k0 < 4; ++k0) {
        bf16x8 a = rv ? ap[k0 * 4] : zero8;
        int m = k0 * 4 + q;
        #pragma unroll
        for (int nt = 0; nt < 8; ++nt) {
            int col = nt * 16 + c15;
            bf16x8 b = *(const bf16x8*)&Wl[col * 128 + ((m ^ (col & 7)) << 3)];
            acc[nt] = __builtin_amdgcn_mfma_f32_16x16x32_bf16(a, b, acc[nt], 0, 0, 0);
        }
    }

    int orow0 = r0 + q * 4;
    if (MODE == 1) {
        #pragma unroll
        for (int nt = 0; nt < 8; ++nt) {
            int col = nt * 16 + c15;
            float bv = bias[col];
            #pragma unroll
            for (int r = 0; r < 4; ++r) {
                int ro = orow0 + r;
                if (ro < n) {
                    float v = fmaxf(acc[nt][r] + bv, 0.f);
                    outbf[(size_t)ro * FEAT + col] = f2bf(v);
                }
            }
        }
    } else {
        // fused pool: rowdot = relu(row)·weff ; per-graph LDS accumulation.
        __shared__ float gsum[64];
        int r0b = blockIdx.x * 64;
        int lastn = r0b + 63 < n - 1 ? r0b + 63 : n - 1;
        int gmin = batch[r0b];
        int gmax = batch[lastn];
        int span = gmax - gmin + 1;
        bool lds_ok = (span <= 64);
        if (lds_ok) for (int i = tid; i < span; i += 256) gsum[i] = 0.f;
        __syncthreads();
        float rowdot[4] = {0.f, 0.f, 0.f, 0.f};
        #pragma unroll
        for (int nt = 0; nt < 8; ++nt) {
            int col = nt * 16 + c15;
            float bv = bias[col];
            float wv = weff[col];
            #pragma unroll
            for (int r = 0; r < 4; ++r)
                rowdot[r] += fmaxf(acc[nt][r] + bv, 0.f) * wv;
        }
        #pragma unroll
        for (int r = 0; r < 4; ++r) {
            float v = rowdot[r];
            v += __shfl_xor(v, 1, 64);
            v += __shfl_xor(v, 2, 64);
            v += __shfl_xor(v, 4, 64);
            v += __shfl_xor(v, 8, 64);
            if (c15 == 0) {
                int node = orow0 + r;
                if (node < n) {
                    int g = batch[node];
                    if (lds_ok) atomicAdd(&gsum[g - gmin], v);
                    else        atomicAdd(&sums[g], v);
                }
            }
        }
        __syncthreads();
        if (lds_ok)
            for (int i = tid; i < span; i += 256) atomicAdd(&sums[gmin + i], gsum[i]);
    }
}

// ---------------- finalize: out[g] = sums/cnt + b2.fcw + fcb ----------------
__global__ void finalize_kernel(const float* __restrict__ sums, const int* __restrict__ gstart,
                                const float* __restrict__ weff, const float* __restrict__ fcb,
                                float* __restrict__ out, int G) {
    int g = blockIdx.x * blockDim.x + threadIdx.x;
    if (g >= G) return;
    int cnt = gstart[g + 1] - gstart[g];
    out[g] = (cnt > 0) ? sums[g] / (float)cnt + weff[128] + fcb[0] : fcb[0];
}

static inline size_t align256(size_t x) { return (x + 255) & ~(size_t)255; }

extern "C" void kernel_launch(void* const* d_in, const int* in_sizes, int n_in,
                              void* d_out, int out_size, void* d_ws, size_t ws_size,
                              hipStream_t stream) {
    const float* x      = (const float*)d_in[0];
    const int*   ei     = (const int*)d_in[1];
    const int*   batch  = (const int*)d_in[2];
    const float* W1[3]  = {(const float*)d_in[3],  (const float*)d_in[8],  (const float*)d_in[13]};
    const float* b1[3]  = {(const float*)d_in[4],  (const float*)d_in[9],  (const float*)d_in[14]};
    const float* W2[3]  = {(const float*)d_in[5],  (const float*)d_in[10], (const float*)d_in[15]};
    const float* b2[3]  = {(const float*)d_in[6],  (const float*)d_in[11], (const float*)d_in[16]};
    const float* eps[3] = {(const float*)d_in[7],  (const float*)d_in[12], (const float*)d_in[17]};
    const float* fcw    = (const float*)d_in[18];
    const float* fcb    = (const float*)d_in[19];
    float* out = (float*)d_out;

    const int N = in_sizes[0] / FEAT;
    const int E = in_sizes[1] / 2;
    const int G = out_size;
    const int nbuckets = (N + 63) >> 6;

    // workspace layout
    char* p = (char*)d_ws;
    int* off    = (int*)p;  p += align256((size_t)(N + 1) * 4);
    int* srcs   = (int*)p;  p += align256((size_t)E * 4);
    int* bsums  = (int*)p;  p += align256((size_t)1024 * 4);
    int* gstart = (int*)p;  p += align256((size_t)(G + 1) * 4);
    float* weff = (float*)p; p += align256((size_t)256 * 4);
    unsigned short* Wswz = (unsigned short*)p; p += align256((size_t)5 * 16384 * 2);
    float* sums = (float*)p;                     // zero-init region start
    char* z0 = (char*)sums;
    p += align256((size_t)G * 4);
    int* bcnt = (int*)p; p += align256((size_t)nbuckets * 16 * 4);
    size_t zbytes = (size_t)(p - z0);            // sums + bcnt in one memset
    unsigned int* bpairs = (unsigned int*)p;     p += align256((size_t)nbuckets * BCAP * 4);
    unsigned int* x_bf   = (unsigned int*)p;     p += align256((size_t)N * 64 * 4);
    unsigned int* pre_bf = (unsigned int*)p;     p += align256((size_t)N * 64 * 4);
    unsigned int* t_bf   = (unsigned int*)p;     p += align256((size_t)N * 64 * 4);
    unsigned int* h_bf   = (unsigned int*)p;     p += align256((size_t)N * 64 * 4);
    (void)ws_size; (void)n_in;

    const int* src = ei;        // edge_index[0]
    const int* dst = ei + E;    // edge_index[1]

    hipMemsetAsync(z0, 0, zbytes, stream);

    // CSR build: LDS-binned bucket -> deg -> scan -> bucket_scatter
    const int nb = (N + 1023) / 1024;
    const int nchunks = (E + CHUNK - 1) / CHUNK;
    bucket_kernel<<<nchunks, 256, 0, stream>>>(src, dst, bcnt, bpairs, E);
    deg_kernel<<<nbuckets, 256, 0, stream>>>(bcnt, bpairs, off, N);
    block_sum_kernel<<<nb, 256, 0, stream>>>(off, bsums, N);
    scan_blocksums_kernel<<<1, 1024, 0, stream>>>(bsums, nb, off, N);
    block_scan_kernel<<<nb, 256, 0, stream>>>(off, bsums, N);
    bucket_scatter_kernel<<<nbuckets, 256, 0, stream>>>(bcnt, bpairs, off, srcs, N);

    // fused setup (independent of CSR): xbf | gstart | weff | wprep
    long pairs = (long)N * 64;
    int nxb = (int)((pairs + 255) / 256);
    setup_kernel<<<nxb + 43, 256, 0, stream>>>(
        x, x_bf, pairs, nxb, batch, gstart, N, G,
        W2[2], b2[2], fcw, weff,
        W1[0], W2[0], W1[1], W2[1], W1[2], Wswz);

    const int aggBlocks  = (N + 3) / 4;
    const int gemmBlocks = (N + 63) / 64;
    const unsigned short* Wz[5] = {Wswz, Wswz + 16384, Wswz + 2 * 16384,
                                   Wswz + 3 * 16384, Wswz + 4 * 16384};

    // layers 0,1: agg -> gemm1(bf16) -> gemm2(bf16)
    const unsigned int* h = x_bf;
    for (int i = 0; i < 2; ++i) {
        agg_kernel<<<aggBlocks, 256, 0, stream>>>(h, off, srcs, eps[i], pre_bf, N);
        mfma_mlp_kernel<1><<<gemmBlocks, 256, 0, stream>>>(
            (const unsigned short*)pre_bf, Wz[2 * i], b1[i], (unsigned short*)t_bf,
            nullptr, nullptr, nullptr, N);
        mfma_mlp_kernel<1><<<gemmBlocks, 256, 0, stream>>>(
            (const unsigned short*)t_bf, Wz[2 * i + 1], b2[i], (unsigned short*)h_bf,
            nullptr, nullptr, nullptr, N);
        h = h_bf;
    }
    // layer 2: agg -> gemm1 with fused pooled-dot epilogue (W2_2+fc folded via weff)
    agg_kernel<<<aggBlocks, 256, 0, stream>>>(h, off, srcs, eps[2], pre_bf, N);
    mfma_mlp_kernel<2><<<gemmBlocks, 256, 0, stream>>>(
        (const unsigned short*)pre_bf, Wz[4], b1[2], nullptr,
        batch, weff, sums, N);

    finalize_kernel<<<(G + 255) / 256, 256, 0, stream>>>(sums, gstart, weff, fcb, out, G);
}

// Round 9
// 324.490 us; speedup vs baseline: 1.1153x; 1.1153x over previous
//
#include <hip/hip_runtime.h>

// GIN regressor: 3x [segment-sum aggregation -> (1+eps)*x+agg -> Linear/ReLU/Linear]
// -> global mean pool -> fc.
// CSR built once per call via LDS-binned coarse-bucket counting sort. Round-8
// lesson: the LDS binning fixed write amplification (40MB->6.5MB) but starved
// the GPU (79 blocks x 4 waves, occupancy 3%). This round: same 79 chunks with
// 1024 threads/block (16 waves) -> 4x latency hiding, one scan counter/thread.
// Aggregation gather-only over bf16 tables. GEMMs = bf16 MFMA, pre-swizzled W.
// Layer-2: second GEMM folded into pool (weff = W2@fcw); its first GEMM's
// epilogue computes pooled per-graph sums directly.

#define FEAT 128
#define BCAP 2048          // per-bucket capacity (mean load ~1024)
#define CHUNK 10240        // edges per bucket-kernel block

typedef short  bf16x8 __attribute__((ext_vector_type(8)));
typedef float  f32x4  __attribute__((ext_vector_type(4)));

__device__ inline unsigned short f2bf(float f) {  // round-to-nearest-even fp32->bf16
    unsigned int u = __float_as_uint(f);
    u = (u + 0x7FFFu + ((u >> 16) & 1u)) >> 16;
    return (unsigned short)u;
}
__device__ inline float2 bfpair(unsigned int u) { // packed 2x bf16 -> 2x fp32
    float2 r;
    r.x = __uint_as_float(u << 16);
    r.y = __uint_as_float(u & 0xffff0000u);
    return r;
}

// ---------------- CSR build: LDS-binned coarse-bucket counting sort ----------
// Phase 1: per-chunk LDS bin by dst>>6, then coalesced run writes. 1024 threads.
__global__ __launch_bounds__(1024) void bucket_kernel(
    const int* __restrict__ src, const int* __restrict__ dst,
    int* __restrict__ bcnt, unsigned int* __restrict__ bpairs, int E) {
    __shared__ unsigned int lpairs[CHUNK];   // 40KB: bucket-ordered pairs
    __shared__ int lbase[1025];              // chunk-local exclusive offsets
    __shared__ int lcur[1024];               // counters, then cursors
    __shared__ int lres[1024];               // global reservation base per bucket
    __shared__ int part[1024];
    int tid = threadIdx.x;
    int e0 = blockIdx.x * CHUNK;
    int e1 = e0 + CHUNK; if (e1 > E) e1 = E;
    int cnt = e1 - e0;
    lcur[tid] = 0;
    __syncthreads();
    for (int e = e0 + tid; e < e1; e += 1024) atomicAdd(&lcur[dst[e] >> 6], 1);
    __syncthreads();
    // inclusive Hillis-Steele over 1024 counters (one per thread)
    int v = lcur[tid];
    part[tid] = v;
    __syncthreads();
    for (int d = 1; d < 1024; d <<= 1) {
        int u = (tid >= d) ? part[tid - d] : 0;
        __syncthreads();
        part[tid] += u;
        __syncthreads();
    }
    int ex = part[tid] - v;                  // exclusive
    lbase[tid] = ex;
    if (tid == 1023) lbase[1024] = part[1023];
    lcur[tid] = ex;
    lres[tid] = (v > 0) ? atomicAdd(&bcnt[tid * 16], v) : 0;
    __syncthreads();
    // place pairs bucket-ordered in LDS
    for (int e = e0 + tid; e < e1; e += 1024) {
        int d = dst[e], s = src[e];
        int p = atomicAdd(&lcur[d >> 6], 1);
        lpairs[p] = ((unsigned int)s << 6) | (unsigned int)(d & 63);
    }
    __syncthreads();
    // coalesced writeout: consecutive j -> consecutive slots of the same run
    for (int j = tid; j < cnt; j += 1024) {
        int lo = 0, hi = 1023;
        while (lo < hi) { int m = (lo + hi + 1) >> 1; if (lbase[m] <= j) lo = m; else hi = m - 1; }
        int gpos = lres[lo] + (j - lbase[lo]);
        if (gpos < BCAP) bpairs[(size_t)lo * BCAP + gpos] = lpairs[j];
    }
}

// Phase 2: per-bucket LDS histogram -> node degrees.
__global__ __launch_bounds__(256) void deg_kernel(const int* __restrict__ bcnt,
                                                  const unsigned int* __restrict__ bpairs,
                                                  int* __restrict__ off, int n) {
    __shared__ int lh[64];
    int b = blockIdx.x, tid = threadIdx.x;
    if (tid < 64) lh[tid] = 0;
    __syncthreads();
    int cnt = bcnt[b * 16]; if (cnt > BCAP) cnt = BCAP;
    const unsigned int* bp = bpairs + (size_t)b * BCAP;
    for (int i = tid; i < cnt; i += 256) atomicAdd(&lh[bp[i] & 63u], 1);
    __syncthreads();
    if (tid < 64) {
        int node = b * 64 + tid;
        if (node < n) off[node] = lh[tid];
    }
}

// Phase A: blocksums[b] = sum(off[b*1024 .. +1023])
__global__ void block_sum_kernel(const int* __restrict__ off, int* __restrict__ bs, int n) {
    int b = blockIdx.x, t = threadIdx.x;   // 256 threads
    int base = b * 1024;
    int s = 0;
    #pragma unroll
    for (int i = 0; i < 4; ++i) {
        int idx = base + t + 256 * i;
        if (idx < n) s += off[idx];
    }
    #pragma unroll
    for (int d = 32; d; d >>= 1) s += __shfl_down(s, d, 64);
    __shared__ int ws[4];
    if ((t & 63) == 0) ws[t >> 6] = s;
    __syncthreads();
    if (t == 0) bs[b] = ws[0] + ws[1] + ws[2] + ws[3];
}

__global__ void scan_blocksums_kernel(int* __restrict__ bs, int nb,
                                      int* __restrict__ off, int n) {
    __shared__ int l[1024];
    int t = threadIdx.x;
    int v = (t < nb) ? bs[t] : 0;
    l[t] = v;
    __syncthreads();
    for (int d = 1; d < 1024; d <<= 1) {
        int u = (t >= d) ? l[t - d] : 0;
        __syncthreads();
        l[t] += u;
        __syncthreads();
    }
    if (t < nb) bs[t] = (t == 0) ? 0 : l[t - 1];
    if (t == 1023) off[n] = l[1023];
}

__global__ __launch_bounds__(256) void block_scan_kernel(
    int* __restrict__ off, const int* __restrict__ bs, int n) {
    __shared__ int l[1024];
    __shared__ int part[256];
    int b = blockIdx.x, t = threadIdx.x;
    int base = b * 1024;
    #pragma unroll
    for (int i = 0; i < 4; ++i) {
        int idx = base + t + 256 * i;
        l[t + 256 * i] = (idx < n) ? off[idx] : 0;
    }
    __syncthreads();
    int v0 = l[4 * t], v1 = l[4 * t + 1], v2 = l[4 * t + 2], v3 = l[4 * t + 3];
    int p = v0 + v1 + v2 + v3;
    part[t] = p;
    __syncthreads();
    for (int d = 1; d < 256; d <<= 1) {
        int u = (t >= d) ? part[t - d] : 0;
        __syncthreads();
        part[t] += u;
        __syncthreads();
    }
    int ex = bs[b] + ((t == 0) ? 0 : part[t - 1]);
    int e0 = ex, e1 = ex + v0, e2 = e1 + v1, e3 = e2 + v2;
    int idx = base + 4 * t;
    if (idx + 3 < n) {
        ((int4*)(off + idx))[0] = make_int4(e0, e1, e2, e3);
    } else {
        if (idx + 0 < n) off[idx + 0] = e0;
        if (idx + 1 < n) off[idx + 1] = e1;
        if (idx + 2 < n) off[idx + 2] = e2;
    }
}

// Phase 3: per-bucket scatter with LDS cursors; writes confined to ~4KB region.
__global__ __launch_bounds__(256) void bucket_scatter_kernel(
    const int* __restrict__ bcnt, const unsigned int* __restrict__ bpairs,
    const int* __restrict__ off, int* __restrict__ srcs, int n) {
    __shared__ int lcur[64];
    int b = blockIdx.x, tid = threadIdx.x;
    if (tid < 64) {
        int node = b * 64 + tid;
        lcur[tid] = (node < n) ? off[node] : 0;
    }
    __syncthreads();
    int cnt = bcnt[b * 16]; if (cnt > BCAP) cnt = BCAP;
    const unsigned int* bp = bpairs + (size_t)b * BCAP;
    for (int i = tid; i < cnt; i += 256) {
        unsigned int pr = bp[i];
        int pos = atomicAdd(&lcur[pr & 63u], 1);
        srcs[pos] = (int)(pr >> 6);
    }
}

// ---------------- fused setup: xbf | gstart | weff | wprep ----------------
__global__ __launch_bounds__(256) void setup_kernel(
    const float* __restrict__ x, unsigned int* __restrict__ xbf, long pairs, int nxb,
    const int* __restrict__ batch, int* __restrict__ gstart, int n, int G,
    const float* __restrict__ W2f, const float* __restrict__ b2f,
    const float* __restrict__ fcw, float* __restrict__ weff,
    const float* __restrict__ W0, const float* __restrict__ W1,
    const float* __restrict__ W2, const float* __restrict__ W3,
    const float* __restrict__ W4, unsigned short* __restrict__ Wswz) {
    int b = blockIdx.x, tid = threadIdx.x;
    if (b < nxb) {                       // cast x -> packed bf16
        long i = (long)b * 256 + tid;
        if (i < pairs) {
            float2 v = ((const float2*)x)[i];
            xbf[i] = (unsigned int)f2bf(v.x) | ((unsigned int)f2bf(v.y) << 16);
        }
    } else if (b < nxb + 2) {            // gstart[g] = lower_bound(batch, g)
        int i = (b - nxb) * 256 + tid;
        if (i <= G) {
            int lo = 0, hi = n;
            while (lo < hi) { int m = (lo + hi) >> 1; if (batch[m] < i) lo = m + 1; else hi = m; }
            gstart[i] = lo;
        }
    } else if (b == nxb + 2) {           // weff = W2@fcw ; weff[128] = b2.fcw
        int lane = tid & 63, wave = tid >> 6;
        float2 f2 = ((const float2*)fcw)[lane];
        for (int r = wave; r < 128; r += 4) {
            float2 w = ((const float2*)(W2f + r * FEAT))[lane];
            float d = w.x * f2.x + w.y * f2.y;
            #pragma unroll
            for (int s = 32; s; s >>= 1) d += __shfl_down(d, s, 64);
            if (lane == 0) weff[r] = d;
        }
        if (wave == 0) {
            float2 bb = ((const float2*)b2f)[lane];
            float d = bb.x * f2.x + bb.y * f2.y;
            #pragma unroll
            for (int s = 32; s; s >>= 1) d += __shfl_down(d, s, 64);
            if (lane == 0) weff[128] = d;
        }
    } else {                             // wprep: swizzled bf16 weights
        int gid = (b - nxb - 3) * 256 + tid;
        if (gid < 5 * 2048) {
            int mat = gid >> 11;
            int task = gid & 2047;
            int c = task >> 4, m = task & 15;
            const float* W = (mat == 0) ? W0 : (mat == 1) ? W1 : (mat == 2) ? W2 :
                             (mat == 3) ? W3 : W4;
            unsigned short* dp = Wswz + mat * 16384 + c * 128 + ((m ^ (c & 7)) << 3);
            #pragma unroll
            for (int j = 0; j < 8; ++j) dp[j] = f2bf(W[(8 * m + j) * FEAT + c]);
        }
    }
}

// ---------------- aggregation + (1+eps)*h -> bf16 pre ----------------
__global__ void agg_kernel(const unsigned int* __restrict__ h, const int* __restrict__ off,
                           const int* __restrict__ srcs, const float* __restrict__ eps_p,
                           unsigned int* __restrict__ pre_bf, int n) {
    int wave = (int)((blockIdx.x * (size_t)blockDim.x + threadIdx.x) >> 6);
    int lane = threadIdx.x & 63;
    if (wave >= n) return;
    float eps1 = 1.0f + eps_p[0];
    float2 self = bfpair(h[(size_t)wave * 64 + lane]);
    float2 acc0 = make_float2(self.x * eps1, self.y * eps1);
    float2 acc1 = make_float2(0.f, 0.f);
    float2 acc2 = make_float2(0.f, 0.f);
    float2 acc3 = make_float2(0.f, 0.f);
    int j0 = off[wave], j1 = off[wave + 1];
    int j = j0;
    for (; j + 8 <= j1; j += 8) {
        int s0 = srcs[j + 0], s1 = srcs[j + 1], s2 = srcs[j + 2], s3 = srcs[j + 3];
        int s4 = srcs[j + 4], s5 = srcs[j + 5], s6 = srcs[j + 6], s7 = srcs[j + 7];
        unsigned int u0 = h[(size_t)s0 * 64 + lane];
        unsigned int u1 = h[(size_t)s1 * 64 + lane];
        unsigned int u2 = h[(size_t)s2 * 64 + lane];
        unsigned int u3 = h[(size_t)s3 * 64 + lane];
        unsigned int u4 = h[(size_t)s4 * 64 + lane];
        unsigned int u5 = h[(size_t)s5 * 64 + lane];
        unsigned int u6 = h[(size_t)s6 * 64 + lane];
        unsigned int u7 = h[(size_t)s7 * 64 + lane];
        float2 v0 = bfpair(u0), v1 = bfpair(u1), v2 = bfpair(u2), v3 = bfpair(u3);
        float2 v4 = bfpair(u4), v5 = bfpair(u5), v6 = bfpair(u6), v7 = bfpair(u7);
        acc0.x += v0.x; acc0.y += v0.y;  acc1.x += v1.x; acc1.y += v1.y;
        acc2.x += v2.x; acc2.y += v2.y;  acc3.x += v3.x; acc3.y += v3.y;
        acc0.x += v4.x; acc0.y += v4.y;  acc1.x += v5.x; acc1.y += v5.y;
        acc2.x += v6.x; acc2.y += v6.y;  acc3.x += v7.x; acc3.y += v7.y;
    }
    for (; j < j1; ++j) {
        int s = srcs[j];
        float2 v = bfpair(h[(size_t)s * 64 + lane]);
        acc0.x += v.x; acc0.y += v.y;
    }
    acc0.x += acc1.x + acc2.x + acc3.x;
    acc0.y += acc1.y + acc2.y + acc3.y;
    pre_bf[(size_t)wave * 64 + lane] =
        (unsigned int)f2bf(acc0.x) | ((unsigned int)f2bf(acc0.y) << 16);
}

// ---------------- bf16 MFMA GEMM (+ReLU). MODE 1: bf16 store. MODE 2: fused pool ----
template <int MODE>
__global__ __launch_bounds__(256) void mfma_mlp_kernel(
    const unsigned short* __restrict__ A, const unsigned short* __restrict__ Wswz,
    const float* __restrict__ bias, unsigned short* __restrict__ outbf,
    const int* __restrict__ batch, const float* __restrict__ weff,
    float* __restrict__ sums, int n) {
    __shared__ int4 Wl4[2048];   // 32KB swizzled W
    int tid = threadIdx.x;
    const int4* ws4 = (const int4*)Wswz;
    #pragma unroll
    for (int i = 0; i < 8; ++i) Wl4[i * 256 + tid] = ws4[i * 256 + tid];
    __syncthreads();
    const unsigned short* Wl = (const unsigned short*)Wl4;

    int lane = tid & 63, wave = tid >> 6;
    int q = lane >> 4, c15 = lane & 15;
    int r0 = blockIdx.x * 64 + wave * 16;
    int arow = r0 + c15;
    bool rv = arow < n;
    const bf16x8* ap = (const bf16x8*)(A + (size_t)arow * FEAT + q * 8);

    f32x4 zf = {0.f, 0.f, 0.f, 0.f};
    f32x4 acc[8];
    #pragma unroll
    for (int i = 0; i < 8; ++i) acc[i] = zf;
    bf16x8 zero8 = {0, 0, 0, 0, 0, 0, 0, 0};

    #pragma unroll
    for (int k0 = 0; k0 < 4; ++k0) {
        bf16x8 a = rv ? ap[k0 * 4] : zero8;
        int m = k0 * 4 + q;
        #pragma unroll
        for (int nt = 0; nt < 8; ++nt) {
            int col = nt * 16 + c15;
            bf16x8 b = *(const bf16x8*)&Wl[col * 128 + ((m ^ (col & 7)) << 3)];
            acc[nt] = __builtin_amdgcn_mfma_f32_16x16x32_bf16(a, b, acc[nt], 0, 0, 0);
        }
    }

    int orow0 = r0 + q * 4;
    if (MODE == 1) {
        #pragma unroll
        for (int nt = 0; nt < 8; ++nt) {
            int col = nt * 16 + c15;
            float bv = bias[col];
            #pragma unroll
            for (int r = 0; r < 4; ++r) {
                int ro = orow0 + r;
                if (ro < n) {
                    float v = fmaxf(acc[nt][r] + bv, 0.f);
                    outbf[(size_t)ro * FEAT + col] = f2bf(v);
                }
            }
        }
    } else {
        // fused pool: rowdot = relu(row)·weff ; per-graph LDS accumulation.
        __shared__ float gsum[64];
        int r0b = blockIdx.x * 64;
        int lastn = r0b + 63 < n - 1 ? r0b + 63 : n - 1;
        int gmin = batch[r0b];
        int gmax = batch[lastn];
        int span = gmax - gmin + 1;
        bool lds_ok = (span <= 64);
        if (lds_ok) for (int i = tid; i < span; i += 256) gsum[i] = 0.f;
        __syncthreads();
        float rowdot[4] = {0.f, 0.f, 0.f, 0.f};
        #pragma unroll
        for (int nt = 0; nt < 8; ++nt) {
            int col = nt * 16 + c15;
            float bv = bias[col];
            float wv = weff[col];
            #pragma unroll
            for (int r = 0; r < 4; ++r)
                rowdot[r] += fmaxf(acc[nt][r] + bv, 0.f) * wv;
        }
        #pragma unroll
        for (int r = 0; r < 4; ++r) {
            float v = rowdot[r];
            v += __shfl_xor(v, 1, 64);
            v += __shfl_xor(v, 2, 64);
            v += __shfl_xor(v, 4, 64);
            v += __shfl_xor(v, 8, 64);
            if (c15 == 0) {
                int node = orow0 + r;
                if (node < n) {
                    int g = batch[node];
                    if (lds_ok) atomicAdd(&gsum[g - gmin], v);
                    else        atomicAdd(&sums[g], v);
                }
            }
        }
        __syncthreads();
        if (lds_ok)
            for (int i = tid; i < span; i += 256) atomicAdd(&sums[gmin + i], gsum[i]);
    }
}

// ---------------- finalize: out[g] = sums/cnt + b2.fcw + fcb ----------------
__global__ void finalize_kernel(const float* __restrict__ sums, const int* __restrict__ gstart,
                                const float* __restrict__ weff, const float* __restrict__ fcb,
                                float* __restrict__ out, int G) {
    int g = blockIdx.x * blockDim.x + threadIdx.x;
    if (g >= G) return;
    int cnt = gstart[g + 1] - gstart[g];
    out[g] = (cnt > 0) ? sums[g] / (float)cnt + weff[128] + fcb[0] : fcb[0];
}

static inline size_t align256(size_t x) { return (x + 255) & ~(size_t)255; }

extern "C" void kernel_launch(void* const* d_in, const int* in_sizes, int n_in,
                              void* d_out, int out_size, void* d_ws, size_t ws_size,
                              hipStream_t stream) {
    const float* x      = (const float*)d_in[0];
    const int*   ei     = (const int*)d_in[1];
    const int*   batch  = (const int*)d_in[2];
    const float* W1[3]  = {(const float*)d_in[3],  (const float*)d_in[8],  (const float*)d_in[13]};
    const float* b1[3]  = {(const float*)d_in[4],  (const float*)d_in[9],  (const float*)d_in[14]};
    const float* W2[3]  = {(const float*)d_in[5],  (const float*)d_in[10], (const float*)d_in[15]};
    const float* b2[3]  = {(const float*)d_in[6],  (const float*)d_in[11], (const float*)d_in[16]};
    const float* eps[3] = {(const float*)d_in[7],  (const float*)d_in[12], (const float*)d_in[17]};
    const float* fcw    = (const float*)d_in[18];
    const float* fcb    = (const float*)d_in[19];
    float* out = (float*)d_out;

    const int N = in_sizes[0] / FEAT;
    const int E = in_sizes[1] / 2;
    const int G = out_size;
    const int nbuckets = (N + 63) >> 6;

    // workspace layout
    char* p = (char*)d_ws;
    int* off    = (int*)p;  p += align256((size_t)(N + 1) * 4);
    int* srcs   = (int*)p;  p += align256((size_t)E * 4);
    int* bsums  = (int*)p;  p += align256((size_t)1024 * 4);
    int* gstart = (int*)p;  p += align256((size_t)(G + 1) * 4);
    float* weff = (float*)p; p += align256((size_t)256 * 4);
    unsigned short* Wswz = (unsigned short*)p; p += align256((size_t)5 * 16384 * 2);
    float* sums = (float*)p;                     // zero-init region start
    char* z0 = (char*)sums;
    p += align256((size_t)G * 4);
    int* bcnt = (int*)p; p += align256((size_t)nbuckets * 16 * 4);
    size_t zbytes = (size_t)(p - z0);            // sums + bcnt in one memset
    unsigned int* bpairs = (unsigned int*)p;     p += align256((size_t)nbuckets * BCAP * 4);
    unsigned int* x_bf   = (unsigned int*)p;     p += align256((size_t)N * 64 * 4);
    unsigned int* pre_bf = (unsigned int*)p;     p += align256((size_t)N * 64 * 4);
    unsigned int* t_bf   = (unsigned int*)p;     p += align256((size_t)N * 64 * 4);
    unsigned int* h_bf   = (unsigned int*)p;     p += align256((size_t)N * 64 * 4);
    (void)ws_size; (void)n_in;

    const int* src = ei;        // edge_index[0]
    const int* dst = ei + E;    // edge_index[1]

    hipMemsetAsync(z0, 0, zbytes, stream);

    // CSR build: LDS-binned bucket (1024 thr) -> deg -> scan -> bucket_scatter
    const int nb = (N + 1023) / 1024;
    const int nchunks = (E + CHUNK - 1) / CHUNK;
    bucket_kernel<<<nchunks, 1024, 0, stream>>>(src, dst, bcnt, bpairs, E);
    deg_kernel<<<nbuckets, 256, 0, stream>>>(bcnt, bpairs, off, N);
    block_sum_kernel<<<nb, 256, 0, stream>>>(off, bsums, N);
    scan_blocksums_kernel<<<1, 1024, 0, stream>>>(bsums, nb, off, N);
    block_scan_kernel<<<nb, 256, 0, stream>>>(off, bsums, N);
    bucket_scatter_kernel<<<nbuckets, 256, 0, stream>>>(bcnt, bpairs, off, srcs, N);

    // fused setup (independent of CSR): xbf | gstart | weff | wprep
    long pairs = (long)N * 64;
    int nxb = (int)((pairs + 255) / 256);
    setup_kernel<<<nxb + 43, 256, 0, stream>>>(
        x, x_bf, pairs, nxb, batch, gstart, N, G,
        W2[2], b2[2], fcw, weff,
        W1[0], W2[0], W1[1], W2[1], W1[2], Wswz);

    const int aggBlocks  = (N + 3) / 4;
    const int gemmBlocks = (N + 63) / 64;
    const unsigned short* Wz[5] = {Wswz, Wswz + 16384, Wswz + 2 * 16384,
                                   Wswz + 3 * 16384, Wswz + 4 * 16384};

    // layers 0,1: agg -> gemm1(bf16) -> gemm2(bf16)
    const unsigned int* h = x_bf;
    for (int i = 0; i < 2; ++i) {
        agg_kernel<<<aggBlocks, 256, 0, stream>>>(h, off, srcs, eps[i], pre_bf, N);
        mfma_mlp_kernel<1><<<gemmBlocks, 256, 0, stream>>>(
            (const unsigned short*)pre_bf, Wz[2 * i], b1[i], (unsigned short*)t_bf,
            nullptr, nullptr, nullptr, N);
        mfma_mlp_kernel<1><<<gemmBlocks, 256, 0, stream>>>(
            (const unsigned short*)t_bf, Wz[2 * i + 1], b2[i], (unsigned short*)h_bf,
            nullptr, nullptr, nullptr, N);
        h = h_bf;
    }
    // layer 2: agg -> gemm1 with fused pooled-dot epilogue (W2_2+fc folded via weff)
    agg_kernel<<<aggBlocks, 256, 0, stream>>>(h, off, srcs, eps[2], pre_bf, N);
    mfma_mlp_kernel<2><<<gemmBlocks, 256, 0, stream>>>(
        (const unsigned short*)pre_bf, Wz[4], b1[2], nullptr,
        batch, weff, sums, N);

    finalize_kernel<<<(G + 255) / 256, 256, 0, stream>>>(sums, gstart, weff, fcb, out, G);
}